// Round 7
// baseline (64.142 us; speedup 1.0000x reference)
//
#include <hip/hip_runtime.h>
#include <hip/hip_bf16.h>

// LengthRegulator, phoneme-centric: x [B=32,T=512,D=512] f32,
// duration [B,T] int32, max_len=4096. out0: [B,ML,D] f32, out1: mel_len [B] f32.
//
// R4/R5 lesson: gather-centric structure forces a choice between plain stores
// (L2 thrash of x: 72.9us) and NT stores (store BW capped ~4.6 TB/s: 58.5us).
// Restructure so each x row is read EXACTLY ONCE (no reuse to protect):
//   - expand blocks: 8 waves/block, one wave per phoneme (b,t). Wave loads
//     its 2KB row into registers, stores it to frames [start,end) — plain
//     stores at the proven 6.9 TB/s fill path.
//   - zerofill blocks: write zeros for frames [mel, ML) — pure stores.
// All blocks redo their batch's 512-scan in a cheap shfl prologue (R3-proven).
// (R6 was a build break: NZERO collides with a glibc macro — renamed.)

typedef float f32x4 __attribute__((ext_vector_type(4)));

constexpr int B   = 32;
constexpr int T   = 512;
constexpr int D   = 512;
constexpr int D4  = D / 4;        // 128 x 16B per row
constexpr int ML  = 4096;
constexpr int NTHREADS = 512;
constexpr int kPhonPerBlock = 8;                     // one per wave
constexpr int kNumExp  = T / kPhonPerBlock;          // 64 expand blocks / batch
constexpr int kZChunk  = 512;                        // frames per zerofill block
constexpr int kNumZero = ML / kZChunk;               // 8 zerofill blocks / batch
constexpr int kBlocksPerBatch = kNumExp + kNumZero;  // 72 blocks per batch

__global__ __launch_bounds__(NTHREADS) void lr_expand(
    const int*   __restrict__ duration,  // [B, T]
    const f32x4* __restrict__ x,         // [B, T, D4]
    f32x4*       __restrict__ out,       // [B, ML, D4]
    float*       __restrict__ mel_out)   // [B]
{
    const int b    = blockIdx.x / kBlocksPerBatch;
    const int r    = blockIdx.x % kBlocksPerBatch;
    const int t    = threadIdx.x;
    const int lane = t & 63;
    const int wave = t >> 6;             // 8 waves

    __shared__ int csum[T];
    __shared__ int wsum[NTHREADS / 64];

    // ---- batch scan prologue: inclusive csum of duration[b,:] ----
    int v = duration[b * T + t];
    #pragma unroll
    for (int off = 1; off < 64; off <<= 1) {
        int n = __shfl_up(v, off, 64);
        if (lane >= off) v += n;
    }
    if (lane == 63) wsum[wave] = v;
    __syncthreads();
    int prev = 0;
    #pragma unroll
    for (int w = 0; w < NTHREADS / 64; ++w)
        if (w < wave) prev += wsum[w];
    v += prev;
    csum[t] = v;
    __syncthreads();

    const int mel = csum[T - 1];

    if (r < kNumExp) {
        // ---- expand: this wave owns phoneme p ----
        const int p     = r * kPhonPerBlock + wave;
        const int end   = csum[p];
        const int start = (p == 0) ? 0 : csum[p - 1];

        if (r == 0 && t == 0)
            mel_out[b] = (float)mel;

        if (end > start) {
            // load row once: 64 lanes x 32B = 2KB
            const size_t xoff = ((size_t)(b * T + p)) * D4 + 2 * lane;
            const f32x4 v0 = x[xoff];
            const f32x4 v1 = x[xoff + 1];
            size_t o = ((size_t)(b * ML + start)) * D4 + 2 * lane;
            for (int j = start; j < end; ++j, o += D4) {
                out[o]     = v0;
                out[o + 1] = v1;
            }
        }
    } else {
        // ---- zerofill: frames [max(j0, mel), j0+kZChunk) ----
        const int c  = r - kNumExp;
        const int j0 = c * kZChunk;
        int fstart = mel - j0;
        if (fstart >= kZChunk) return;       // chunk fully valid
        if (fstart < 0) fstart = 0;
        const int total = (kZChunk - fstart) * D4;
        const size_t base = ((size_t)(b * ML + j0 + fstart)) * D4;
        const f32x4 zero = {0.f, 0.f, 0.f, 0.f};
        for (int m = t; m < total; m += NTHREADS)
            out[base + m] = zero;
    }
}

extern "C" void kernel_launch(void* const* d_in, const int* in_sizes, int n_in,
                              void* d_out, int out_size, void* d_ws, size_t ws_size,
                              hipStream_t stream) {
    const float* x   = (const float*)d_in[0];
    const int*   dur = (const int*)d_in[1];

    float* out     = (float*)d_out;                 // [B*ML*D] then [B]
    float* mel_out = out + (size_t)B * ML * D;

    lr_expand<<<B * kBlocksPerBatch, NTHREADS, 0, stream>>>(
        dur, (const f32x4*)x, (f32x4*)out, mel_out);
}

// Round 8
// 63.689 us; speedup vs baseline: 1.0071x; 1.0071x over previous
//
#include <hip/hip_runtime.h>
#include <hip/hip_bf16.h>

// LengthRegulator, phoneme-centric: x [B=32,T=512,D=512] f32,
// duration [B,T] int32, max_len=4096. out0: [B,ML,D] f32, out1: mel_len [B] f32.
//
// R7 lesson: expand stores used o = base + 2*lane -> each wave store covered a
// 2KB span half-filled (16B per 32B stride) = partial-line writes, 2 L2/HBM
// write transactions per 128B line (ECC RMW). Fix: lane l holds row bytes
// [16l, 16l+16) and [1024+16l, ...) so each store instr is 1KB contiguous
// full-line. Everything else identical to R7.

typedef float f32x4 __attribute__((ext_vector_type(4)));

constexpr int B   = 32;
constexpr int T   = 512;
constexpr int D   = 512;
constexpr int D4  = D / 4;        // 128 x 16B per row
constexpr int ML  = 4096;
constexpr int NTHREADS = 512;
constexpr int kPhonPerBlock = 8;                     // one per wave
constexpr int kNumExp  = T / kPhonPerBlock;          // 64 expand blocks / batch
constexpr int kZChunk  = 512;                        // frames per zerofill block
constexpr int kNumZero = ML / kZChunk;               // 8 zerofill blocks / batch
constexpr int kBlocksPerBatch = kNumExp + kNumZero;  // 72 blocks per batch

__global__ __launch_bounds__(NTHREADS) void lr_expand(
    const int*   __restrict__ duration,  // [B, T]
    const f32x4* __restrict__ x,         // [B, T, D4]
    f32x4*       __restrict__ out,       // [B, ML, D4]
    float*       __restrict__ mel_out)   // [B]
{
    const int b    = blockIdx.x / kBlocksPerBatch;
    const int r    = blockIdx.x % kBlocksPerBatch;
    const int t    = threadIdx.x;
    const int lane = t & 63;
    const int wave = t >> 6;             // 8 waves

    __shared__ int csum[T];
    __shared__ int wsum[NTHREADS / 64];

    // ---- batch scan prologue: inclusive csum of duration[b,:] ----
    int v = duration[b * T + t];
    #pragma unroll
    for (int off = 1; off < 64; off <<= 1) {
        int n = __shfl_up(v, off, 64);
        if (lane >= off) v += n;
    }
    if (lane == 63) wsum[wave] = v;
    __syncthreads();
    int prev = 0;
    #pragma unroll
    for (int w = 0; w < NTHREADS / 64; ++w)
        if (w < wave) prev += wsum[w];
    v += prev;
    csum[t] = v;
    __syncthreads();

    const int mel = csum[T - 1];

    if (r < kNumExp) {
        // ---- expand: this wave owns phoneme p ----
        const int p     = r * kPhonPerBlock + wave;
        const int end   = csum[p];
        const int start = (p == 0) ? 0 : csum[p - 1];

        if (r == 0 && t == 0)
            mel_out[b] = (float)mel;

        if (end > start) {
            // load row once: lane l takes bytes [16l,16l+16) and +1KB
            const size_t xbase = ((size_t)(b * T + p)) * D4;
            const f32x4 v0 = x[xbase + lane];        // first 1KB of row
            const f32x4 v1 = x[xbase + 64 + lane];   // second 1KB of row
            size_t o = ((size_t)(b * ML + start)) * D4;
            for (int j = start; j < end; ++j, o += D4) {
                out[o + lane]      = v0;             // 1KB contiguous/instr
                out[o + 64 + lane] = v1;             // full cache lines
            }
        }
    } else {
        // ---- zerofill: frames [max(j0, mel), j0+kZChunk) ----
        const int c  = r - kNumExp;
        const int j0 = c * kZChunk;
        int fstart = mel - j0;
        if (fstart >= kZChunk) return;       // chunk fully valid
        if (fstart < 0) fstart = 0;
        const int total = (kZChunk - fstart) * D4;
        const size_t base = ((size_t)(b * ML + j0 + fstart)) * D4;
        const f32x4 zero = {0.f, 0.f, 0.f, 0.f};
        for (int m = t; m < total; m += NTHREADS)
            out[base + m] = zero;
    }
}

extern "C" void kernel_launch(void* const* d_in, const int* in_sizes, int n_in,
                              void* d_out, int out_size, void* d_ws, size_t ws_size,
                              hipStream_t stream) {
    const float* x   = (const float*)d_in[0];
    const int*   dur = (const int*)d_in[1];

    float* out     = (float*)d_out;                 // [B*ML*D] then [B]
    float* mel_out = out + (size_t)B * ML * D;

    lr_expand<<<B * kBlocksPerBatch, NTHREADS, 0, stream>>>(
        dur, (const f32x4*)x, (f32x4*)out, mel_out);
}